// Round 20
// baseline (170.443 us; speedup 1.0000x reference)
//
#include <hip/hip_runtime.h>
#include <hip/hip_bf16.h>
#include <math.h>

#define N_NODES 100000
#define N_EDGES 1600000
#define BUCKET_SHIFT 8
#define NBUCKETS ((N_NODES + 255) >> 8)      // 391 buckets of 256 nodes
#define BCAP 6144                            // mean 4096, sigma ~64 -> 32 sigma margin
#define NPROJ_BLOCKS ((N_NODES + 63) / 64)   // 1563 (64 nodes/block, 16/wave)
#define SCAT_BLOCKS ((N_EDGES / 4 + 2047) / 2048)  // 196 (8192 edges/block)
#define CCHUNK 6250u                         // col-chunk width (16 chunks, 0.8 MB/half)
#define NCHUNKS2 ((N_NODES + 127) / 128)     // 782 agg 128-node chunks

typedef unsigned short ushort_t;
typedef __attribute__((ext_vector_type(8))) short bf16x8;   // 8 bf16 in 4 VGPRs
typedef __attribute__((ext_vector_type(4))) float f32x4;

union U8 { uint4 u; bf16x8 b; };

// pack two fp32 -> one uint of 2 bf16 (RTN-even) via compiler-lowered cvt_pk
__device__ inline unsigned pkbf16(float lo, float hi) {
    __hip_bfloat162 h = __float22bfloat162_rn(make_float2(lo, hi));
    return *reinterpret_cast<unsigned*>(&h);
}
__device__ inline float blo(unsigned w) { return __uint_as_float(w << 16); }
__device__ inline float bhi(unsigned w) { return __uint_as_float(w & 0xFFFF0000u); }

// ---------------------------------------------------------------------------
// K0: one-time prep. Transpose Wq/Wk/Wv/Wo (fp32 row-major [k][col]) into
// bf16 Wt[mat][col][k]. Also zeroes bucket cursors.
// ---------------------------------------------------------------------------
__global__ __launch_bounds__(256) void wtrans_kernel(
    const float* __restrict__ Wq, const float* __restrict__ Wk,
    const float* __restrict__ Wv, const float* __restrict__ Wo,
    ushort_t* __restrict__ Wt, int* __restrict__ cursor)
{
    int t = threadIdx.x;
    for (int i = t; i < 512; i += 256) cursor[i] = 0;
    int c = t & 63;
    int k0 = (t >> 6) * 16;
    const float* srcs[4] = {Wq, Wk, Wv, Wo};
    #pragma unroll
    for (int m = 0; m < 4; ++m) {
        const float* Wsrc = srcs[m];
        ushort_t* dst = Wt + m * 4096;
        unsigned p[8];
        #pragma unroll
        for (int j = 0; j < 8; ++j) {
            float lo = Wsrc[(k0 + 2 * j) * 64 + c];
            float hi = Wsrc[(k0 + 2 * j + 1) * 64 + c];
            p[j] = pkbf16(lo, hi);
        }
        *(uint4*)&dst[c * 64 + k0]     = make_uint4(p[0], p[1], p[2], p[3]);
        *(uint4*)&dst[c * 64 + k0 + 8] = make_uint4(p[4], p[5], p[6], p[7]);
    }
}

// ---------------------------------------------------------------------------
// K1: Q/KV projection via MFMA 16x16x32 bf16 (swapped operands; see R13).
// Q stored BF16 (Qb). K/V in two half-head tables (KVlo: heads 0-3,
// KVhi: heads 4-7), 128 B rows.
// ---------------------------------------------------------------------------
__global__ __launch_bounds__(256) void qkv_kernel(
    const float* __restrict__ x, const ushort_t* __restrict__ Wt,
    const float* __restrict__ bq, const float* __restrict__ bk,
    const float* __restrict__ bv,
    ushort_t* __restrict__ Qb, ushort_t* __restrict__ KVlo,
    ushort_t* __restrict__ KVhi)
{
    int tid = threadIdx.x;
    int lane = tid & 63;
    int w = tid >> 6;
    int node = blockIdx.x * 64 + w * 16 + (lane & 15);
    int nclamp = node < N_NODES ? node : N_NODES - 1;
    int koff = (lane >> 4) * 8;

    U8 xf[2];
    #pragma unroll
    for (int kh = 0; kh < 2; ++kh) {
        const float* xb = &x[(size_t)nclamp * 64 + kh * 32 + koff];
        float4 a0 = *(const float4*)xb;
        float4 a1 = *(const float4*)(xb + 4);
        unsigned* xp = (unsigned*)&xf[kh];
        xp[0] = pkbf16(a0.x, a0.y); xp[1] = pkbf16(a0.z, a0.w);
        xp[2] = pkbf16(a1.x, a1.y); xp[3] = pkbf16(a1.z, a1.w);
    }

    f32x4 acc[3][4];
    #pragma unroll
    for (int m = 0; m < 3; ++m)
        #pragma unroll
        for (int ct = 0; ct < 4; ++ct)
            acc[m][ct] = (f32x4){0.f, 0.f, 0.f, 0.f};

    int colin = lane & 15;
    #pragma unroll
    for (int m = 0; m < 3; ++m) {
        const ushort_t* Wm = Wt + m * 4096;
        #pragma unroll
        for (int ct = 0; ct < 4; ++ct) {
            const ushort_t* wb = &Wm[(ct * 16 + colin) * 64 + koff];
            #pragma unroll
            for (int kh = 0; kh < 2; ++kh) {
                U8 wf;
                wf.u = *(const uint4*)(wb + kh * 32);
                acc[m][ct] = __builtin_amdgcn_mfma_f32_16x16x32_bf16(
                    wf.b, xf[kh].b, acc[m][ct], 0, 0, 0);
            }
        }
    }

    if (node < N_NODES) {
        int wc4 = (lane >> 4) * 4;
        #pragma unroll
        for (int ct = 0; ct < 4; ++ct) {
            int wc = ct * 16 + wc4;        // output col: head = wc>>3, dim = wc&7
            float4 qb = *(const float4*)&bq[wc];
            f32x4 a = acc[0][ct];
            *(uint2*)&Qb[(size_t)node * 64 + wc] =
                make_uint2(pkbf16(a[0] + qb.x, a[1] + qb.y),
                           pkbf16(a[2] + qb.z, a[3] + qb.w));
            int hh = wc >> 3;
            ushort_t* kvdst = (hh < 4 ? KVlo : KVhi)
                            + (size_t)node * 64 + (hh & 3) * 8 + (wc & 7);
            float4 kb = *(const float4*)&bk[wc];
            f32x4 k = acc[1][ct];
            *(uint2*)kvdst =
                make_uint2(pkbf16(k[0] + kb.x, k[1] + kb.y),
                           pkbf16(k[2] + kb.z, k[3] + kb.w));
            float4 vb = *(const float4*)&bv[wc];
            f32x4 v = acc[2][ct];
            *(uint2*)(kvdst + 32) =
                make_uint2(pkbf16(v[0] + vb.x, v[1] + vb.y),
                           pkbf16(v[2] + vb.z, v[3] + vb.w));
        }
    }
}

// ---------------------------------------------------------------------------
// Pass 1: bucket scatter, 1024 threads x 8192 edges per block (196 blocks).
// ---------------------------------------------------------------------------
__global__ __launch_bounds__(1024) void scatter_kernel(
    const int* __restrict__ ei, int* __restrict__ cursor,
    unsigned int* __restrict__ pairs)
{
    __shared__ int hist[NBUCKETS];
    __shared__ int bbs[NBUCKETS];
    int t = threadIdx.x;
    for (int i = t; i < NBUCKETS; i += 1024) hist[i] = 0;
    __syncthreads();

    const int4* r4 = (const int4*)ei;
    const int4* c4 = (const int4*)(ei + N_EDGES);
    int ia = blockIdx.x * 2048 + t;
    int ib = ia + 1024;
    bool va = (ia < N_EDGES / 4), vb = (ib < N_EDGES / 4);
    int4 rva = va ? r4[ia] : make_int4(0, 0, 0, 0);
    int4 cva = va ? c4[ia] : make_int4(0, 0, 0, 0);
    int4 rvb = vb ? r4[ib] : make_int4(0, 0, 0, 0);
    int4 cvb = vb ? c4[ib] : make_int4(0, 0, 0, 0);

    int rr[8], cc[8];
    rr[0] = rva.x; rr[1] = rva.y; rr[2] = rva.z; rr[3] = rva.w;
    rr[4] = rvb.x; rr[5] = rvb.y; rr[6] = rvb.z; rr[7] = rvb.w;
    cc[0] = cva.x; cc[1] = cva.y; cc[2] = cva.z; cc[3] = cva.w;
    cc[4] = cvb.x; cc[5] = cvb.y; cc[6] = cvb.z; cc[7] = cvb.w;

    int bkt[8], rnk[8];
    unsigned pk[8];
    #pragma unroll
    for (int j = 0; j < 8; ++j) {
        bool v = (j < 4) ? va : vb;
        int b = rr[j] >> BUCKET_SHIFT;
        bkt[j] = b;
        rnk[j] = v ? atomicAdd(&hist[b], 1) : 0;
        pk[j] = ((unsigned)(rr[j] & 255) << 17) | (unsigned)cc[j];
    }
    __syncthreads();
    for (int i = t; i < NBUCKETS; i += 1024) {
        int h = hist[i];
        if (h) bbs[i] = i * BCAP + atomicAdd(&cursor[i], h);
    }
    __syncthreads();
    #pragma unroll
    for (int j = 0; j < 8; ++j) {
        bool v = (j < 4) ? va : vb;
        if (v) pairs[bbs[bkt[j]] + rnk[j]] = pk[j];
    }
}

// ---------------------------------------------------------------------------
// Pass 2: one block per bucket, 512 threads. Stage pairs in LDS; 4096-bin
// histogram keyed (node_local<<4 | col/6250) -> each node's edge list is
// ordered by 16 col-chunks of 0.8 MB/half (L2 cache blocking for agg).
// Scan over first 256 threads. Writes ordered col ids back IN PLACE.
// ---------------------------------------------------------------------------
__global__ __launch_bounds__(512) void csr_build_kernel(
    unsigned int* __restrict__ pairs, const int* __restrict__ cursor,
    int* __restrict__ deg, int* __restrict__ start)
{
    __shared__ unsigned int lp[BCAP];        // 24 KB
    __shared__ int hist[4096];               // 16 KB
    __shared__ int wsum[4];
    int b = blockIdx.x, t = threadIdx.x;
    int cnt = cursor[b];
    unsigned int* bp = pairs + (size_t)b * BCAP;

    for (int i = t; i < cnt; i += 512) lp[i] = bp[i];
    for (int i = t; i < 4096; i += 512) hist[i] = 0;
    __syncthreads();
    for (int i = t; i < cnt; i += 512) {
        unsigned p = lp[i];
        unsigned col = p & 0x1FFFFu;
        int key = (int)((p >> 17) << 4) | (int)(col / CCHUNK);
        atomicAdd(&hist[key], 1);
    }
    __syncthreads();

    // threads 0..255: thread t owns node-bin t (16 chunk bins)
    if (t < 256) {
        int hv[16];
        int local = 0;
        #pragma unroll
        for (int c = 0; c < 16; ++c) { hv[c] = hist[16 * t + c]; local += hv[c]; }
        int lane = t & 63, w = t >> 6;
        int inc = local;
        #pragma unroll
        for (int off = 1; off < 64; off <<= 1) {
            int u = __shfl_up(inc, off);
            if (lane >= off) inc += u;
        }
        if (lane == 63) wsum[w] = inc;
        __syncthreads();
        int woff = 0;
        for (int i = 0; i < w; ++i) woff += wsum[i];
        int excl = woff + inc - local;
        int node = (b << BUCKET_SHIFT) + t;
        if (node < N_NODES) { deg[node] = local; start[node] = b * BCAP + excl; }
        int run = excl;
        #pragma unroll
        for (int c = 0; c < 16; ++c) { hist[16 * t + c] = run; run += hv[c]; }
    } else {
        __syncthreads();                     // match barrier in the t<256 path
    }
    __syncthreads();
    for (int i = t; i < cnt; i += 512) {
        unsigned p = lp[i];
        unsigned col = p & 0x1FFFFu;
        int key = (int)((p >> 17) << 4) | (int)(col / CCHUNK);
        int pos = atomicAdd(&hist[key], 1);
        bp[pos] = col;
    }
}

// ---------------------------------------------------------------------------
// K6: per-node softmax aggregation, ALL-RESIDENT sweep. Lane = (node-slot =
// lane>>1, head-pair = lane&1): 2 lanes per (node, half), each lane owns 2
// heads (16 acc floats). Total waves = 100k*2/32 = 6256 <= 8192 wave slots
// -> every block resident from t=0 -> all blocks sweep the 16 col-chunks in
// rough lockstep -> each XCD fetches each 0.8 MB chunk ~once (R19's 12504
// waves = 1.53 rounds = 1.5x re-fetch). __launch_bounds__(256,8) pins
// <=64 VGPR for full occupancy. s/acc lane-local, zero cross-lane ops.
// ---------------------------------------------------------------------------
#define DOTQ(KW, Q0,Q1,Q2,Q3,Q4,Q5,Q6,Q7)                                     \
    (blo(KW.x) * Q0 + bhi(KW.x) * Q1 + blo(KW.y) * Q2 + bhi(KW.y) * Q3        \
   + blo(KW.z) * Q4 + bhi(KW.z) * Q5 + blo(KW.w) * Q6 + bhi(KW.w) * Q7)

__global__ __launch_bounds__(256, 8) void agg_kernel(
    const ushort_t* __restrict__ Qb, const ushort_t* __restrict__ KVlo,
    const ushort_t* __restrict__ KVhi,
    const int* __restrict__ start, const int* __restrict__ deg,
    const int* __restrict__ elist, ushort_t* __restrict__ aggb)
{
    int bid = blockIdx.x;
    int grp = bid & 7;
    int half = grp >> 2;                     // XCDs 0-3 -> lo, 4-7 -> hi
    int k = (bid >> 3) * 4 + (grp & 3);      // 128-node chunk id
    if (k >= NCHUNKS2) return;

    int tid = threadIdx.x;
    int lane = tid & 63;
    int ns = lane >> 1;                      // node slot 0..31
    int hp = lane & 1;                       // head-pair within half
    int n = k * 128 + (tid >> 6) * 32 + ns;
    bool valid = n < N_NODES;
    int nc = valid ? n : N_NODES - 1;

    int d = deg[nc];
    int st = start[nc];
    const ushort_t* KV = (half ? KVhi : KVlo);
    int hoff = hp * 16;                      // ushort offset of head-pair in K region

    const ushort_t* qp = &Qb[(size_t)nc * 64 + (half * 4 + hp * 2) * 8];
    uint4 qA = *(const uint4*)qp;
    uint4 qB = *(const uint4*)(qp + 8);
    float a0 = blo(qA.x), a1 = bhi(qA.x), a2 = blo(qA.y), a3 = bhi(qA.y);
    float a4 = blo(qA.z), a5 = bhi(qA.z), a6 = blo(qA.w), a7 = bhi(qA.w);
    float b0 = blo(qB.x), b1 = bhi(qB.x), b2 = blo(qB.y), b3 = bhi(qB.y);
    float b4 = blo(qB.z), b5 = bhi(qB.z), b6 = blo(qB.w), b7 = bhi(qB.w);

    const float inv_scale = 0.35355339059327373f;  // 1/sqrt(8)
    float sA = 0.f, sB = 0.f;
    float accA[8] = {0.f, 0.f, 0.f, 0.f, 0.f, 0.f, 0.f, 0.f};
    float accB[8] = {0.f, 0.f, 0.f, 0.f, 0.f, 0.f, 0.f, 0.f};

    for (int j = 0; j < d; ++j) {
        int c = elist[st + j];
        const ushort_t* r = KV + (size_t)c * 64 + hoff;
        uint4 kwA = *(const uint4*)r;
        uint4 kwB = *(const uint4*)(r + 8);
        uint4 vwA = *(const uint4*)(r + 32);
        uint4 vwB = *(const uint4*)(r + 40);
        float dA = DOTQ(kwA, a0, a1, a2, a3, a4, a5, a6, a7);
        float dB = DOTQ(kwB, b0, b1, b2, b3, b4, b5, b6, b7);
        float pA = __expf(dA * inv_scale);
        float pB = __expf(dB * inv_scale);
        sA += pA; sB += pB;
        accA[0] = fmaf(pA, blo(vwA.x), accA[0]);
        accA[1] = fmaf(pA, bhi(vwA.x), accA[1]);
        accA[2] = fmaf(pA, blo(vwA.y), accA[2]);
        accA[3] = fmaf(pA, bhi(vwA.y), accA[3]);
        accA[4] = fmaf(pA, blo(vwA.z), accA[4]);
        accA[5] = fmaf(pA, bhi(vwA.z), accA[5]);
        accA[6] = fmaf(pA, blo(vwA.w), accA[6]);
        accA[7] = fmaf(pA, bhi(vwA.w), accA[7]);
        accB[0] = fmaf(pB, blo(vwB.x), accB[0]);
        accB[1] = fmaf(pB, bhi(vwB.x), accB[1]);
        accB[2] = fmaf(pB, blo(vwB.y), accB[2]);
        accB[3] = fmaf(pB, bhi(vwB.y), accB[3]);
        accB[4] = fmaf(pB, blo(vwB.z), accB[4]);
        accB[5] = fmaf(pB, bhi(vwB.z), accB[5]);
        accB[6] = fmaf(pB, blo(vwB.w), accB[6]);
        accB[7] = fmaf(pB, bhi(vwB.w), accB[7]);
    }

    if (valid) {
        float iA = 1.f / (sA + 1e-8f);
        float iB = 1.f / (sB + 1e-8f);
        ushort_t* op = &aggb[(size_t)n * 64 + (half * 4 + hp * 2) * 8];
        *(uint4*)op = make_uint4(
            pkbf16(accA[0] * iA, accA[1] * iA), pkbf16(accA[2] * iA, accA[3] * iA),
            pkbf16(accA[4] * iA, accA[5] * iA), pkbf16(accA[6] * iA, accA[7] * iA));
        *(uint4*)(op + 8) = make_uint4(
            pkbf16(accB[0] * iB, accB[1] * iB), pkbf16(accB[2] * iB, accB[3] * iB),
            pkbf16(accB[4] * iB, accB[5] * iB), pkbf16(accB[6] * iB, accB[7] * iB));
    }
}

// ---------------------------------------------------------------------------
// K7: output projection via MFMA. B-fragments load DIRECTLY from bf16 aggb.
// ---------------------------------------------------------------------------
__global__ __launch_bounds__(256) void out_kernel(
    const ushort_t* __restrict__ aggb, const ushort_t* __restrict__ Wto,
    const float* __restrict__ bo, float* __restrict__ out)
{
    int tid = threadIdx.x;
    int lane = tid & 63;
    int w = tid >> 6;
    int node = blockIdx.x * 64 + w * 16 + (lane & 15);
    int nclamp = node < N_NODES ? node : N_NODES - 1;
    int koff = (lane >> 4) * 8;

    U8 af[2];
    #pragma unroll
    for (int kh = 0; kh < 2; ++kh)
        af[kh].u = *(const uint4*)&aggb[(size_t)nclamp * 64 + kh * 32 + koff];

    f32x4 acc[4];
    #pragma unroll
    for (int ct = 0; ct < 4; ++ct) acc[ct] = (f32x4){0.f, 0.f, 0.f, 0.f};

    int colin = lane & 15;
    #pragma unroll
    for (int ct = 0; ct < 4; ++ct) {
        const ushort_t* wb = &Wto[(ct * 16 + colin) * 64 + koff];
        #pragma unroll
        for (int kh = 0; kh < 2; ++kh) {
            U8 wf;
            wf.u = *(const uint4*)(wb + kh * 32);
            acc[ct] = __builtin_amdgcn_mfma_f32_16x16x32_bf16(
                wf.b, af[kh].b, acc[ct], 0, 0, 0);
        }
    }

    if (node < N_NODES) {
        int wc4 = (lane >> 4) * 4;
        #pragma unroll
        for (int ct = 0; ct < 4; ++ct) {
            int wc = ct * 16 + wc4;
            float4 ob = *(const float4*)&bo[wc];
            f32x4 a = acc[ct];
            *(float4*)&out[(size_t)node * 64 + wc] =
                make_float4(a[0] + ob.x, a[1] + ob.y, a[2] + ob.z, a[3] + ob.w);
        }
    }
}

extern "C" void kernel_launch(void* const* d_in, const int* in_sizes, int n_in,
                              void* d_out, int out_size, void* d_ws, size_t ws_size,
                              hipStream_t stream)
{
    const float* x  = (const float*)d_in[0];
    const int*   ei = (const int*)  d_in[1];   // [2*E] flattened: row then col
    const float* Wq = (const float*)d_in[2];
    const float* bq = (const float*)d_in[3];
    const float* Wk = (const float*)d_in[4];
    const float* bk = (const float*)d_in[5];
    const float* Wv = (const float*)d_in[6];
    const float* bv = (const float*)d_in[7];
    const float* Wo = (const float*)d_in[8];
    const float* bo = (const float*)d_in[9];
    float* out = (float*)d_out;

    ushort_t* Qb   = (ushort_t*)d_ws;                      // N*64 bf16   12.8 MB
    ushort_t* KVlo = Qb + (size_t)N_NODES * 64;            // N*64 bf16   12.8 MB
    ushort_t* KVhi = KVlo + (size_t)N_NODES * 64;          // N*64 bf16   12.8 MB
    ushort_t* aggb = KVhi + (size_t)N_NODES * 64;          // N*64 bf16   12.8 MB
    int* deg    = (int*)(aggb + (size_t)N_NODES * 64);
    int* start  = deg + N_NODES;
    int* cursor = start + N_NODES;                         // 512 ints
    unsigned int* pairs = (unsigned int*)(cursor + 512);   // NBUCKETS*BCAP (elist aliases)
    ushort_t* Wt = (ushort_t*)(pairs + (size_t)NBUCKETS * BCAP);  // 4*64*64 bf16

    wtrans_kernel<<<1, 256, 0, stream>>>(Wq, Wk, Wv, Wo, Wt, cursor);
    qkv_kernel<<<NPROJ_BLOCKS, 256, 0, stream>>>(x, Wt, bq, bk, bv, Qb, KVlo, KVhi);
    scatter_kernel<<<SCAT_BLOCKS, 1024, 0, stream>>>(ei, cursor, pairs);
    csr_build_kernel<<<NBUCKETS, 512, 0, stream>>>(pairs, cursor, deg, start);
    agg_kernel<<<((NCHUNKS2 + 3) / 4) * 8, 256, 0, stream>>>(
        Qb, KVlo, KVhi, start, deg, (const int*)pairs, aggb);
    out_kernel<<<NPROJ_BLOCKS, 256, 0, stream>>>(aggb, Wt + 3 * 4096, bo, out);
}

// Round 21
// 141.357 us; speedup vs baseline: 1.2058x; 1.2058x over previous
//
#include <hip/hip_runtime.h>
#include <hip/hip_bf16.h>
#include <math.h>

#define N_NODES 100000
#define N_EDGES 1600000
#define BUCKET_SHIFT 8
#define NBUCKETS ((N_NODES + 255) >> 8)      // 391 buckets of 256 nodes
#define BCAP 6144                            // mean 4096, sigma ~64 -> 32 sigma margin
#define NPROJ_BLOCKS ((N_NODES + 63) / 64)   // 1563 (64 nodes/block, 16/wave)
#define SCAT_BLOCKS ((N_EDGES / 4 + 2047) / 2048)  // 196 (8192 edges/block)
#define NCHUNKS 1563                         // agg 64-node chunks
#define CCHUNK 6250u                         // col-chunk width (16 chunks, 0.8 MB/half)

typedef unsigned short ushort_t;
typedef __attribute__((ext_vector_type(8))) short bf16x8;   // 8 bf16 in 4 VGPRs
typedef __attribute__((ext_vector_type(4))) float f32x4;

union U8 { uint4 u; bf16x8 b; };

// pack two fp32 -> one uint of 2 bf16 (RTN-even) via compiler-lowered cvt_pk
__device__ inline unsigned pkbf16(float lo, float hi) {
    __hip_bfloat162 h = __float22bfloat162_rn(make_float2(lo, hi));
    return *reinterpret_cast<unsigned*>(&h);
}
__device__ inline float blo(unsigned w) { return __uint_as_float(w << 16); }
__device__ inline float bhi(unsigned w) { return __uint_as_float(w & 0xFFFF0000u); }

// ---------------------------------------------------------------------------
// K0: one-time prep. Transpose Wq/Wk/Wv/Wo (fp32 row-major [k][col]) into
// bf16 Wt[mat][col][k]. Also zeroes bucket cursors.
// ---------------------------------------------------------------------------
__global__ __launch_bounds__(256) void wtrans_kernel(
    const float* __restrict__ Wq, const float* __restrict__ Wk,
    const float* __restrict__ Wv, const float* __restrict__ Wo,
    ushort_t* __restrict__ Wt, int* __restrict__ cursor)
{
    int t = threadIdx.x;
    for (int i = t; i < 512; i += 256) cursor[i] = 0;
    int c = t & 63;
    int k0 = (t >> 6) * 16;
    const float* srcs[4] = {Wq, Wk, Wv, Wo};
    #pragma unroll
    for (int m = 0; m < 4; ++m) {
        const float* Wsrc = srcs[m];
        ushort_t* dst = Wt + m * 4096;
        unsigned p[8];
        #pragma unroll
        for (int j = 0; j < 8; ++j) {
            float lo = Wsrc[(k0 + 2 * j) * 64 + c];
            float hi = Wsrc[(k0 + 2 * j + 1) * 64 + c];
            p[j] = pkbf16(lo, hi);
        }
        *(uint4*)&dst[c * 64 + k0]     = make_uint4(p[0], p[1], p[2], p[3]);
        *(uint4*)&dst[c * 64 + k0 + 8] = make_uint4(p[4], p[5], p[6], p[7]);
    }
}

// ---------------------------------------------------------------------------
// K1: Q/KV projection via MFMA 16x16x32 bf16 (swapped operands; see R13).
// Q stored BF16 (Qb). K/V in two half-head tables (KVlo: heads 0-3,
// KVhi: heads 4-7), 128 B rows.
// ---------------------------------------------------------------------------
__global__ __launch_bounds__(256) void qkv_kernel(
    const float* __restrict__ x, const ushort_t* __restrict__ Wt,
    const float* __restrict__ bq, const float* __restrict__ bk,
    const float* __restrict__ bv,
    ushort_t* __restrict__ Qb, ushort_t* __restrict__ KVlo,
    ushort_t* __restrict__ KVhi)
{
    int tid = threadIdx.x;
    int lane = tid & 63;
    int w = tid >> 6;
    int node = blockIdx.x * 64 + w * 16 + (lane & 15);
    int nclamp = node < N_NODES ? node : N_NODES - 1;
    int koff = (lane >> 4) * 8;

    U8 xf[2];
    #pragma unroll
    for (int kh = 0; kh < 2; ++kh) {
        const float* xb = &x[(size_t)nclamp * 64 + kh * 32 + koff];
        float4 a0 = *(const float4*)xb;
        float4 a1 = *(const float4*)(xb + 4);
        unsigned* xp = (unsigned*)&xf[kh];
        xp[0] = pkbf16(a0.x, a0.y); xp[1] = pkbf16(a0.z, a0.w);
        xp[2] = pkbf16(a1.x, a1.y); xp[3] = pkbf16(a1.z, a1.w);
    }

    f32x4 acc[3][4];
    #pragma unroll
    for (int m = 0; m < 3; ++m)
        #pragma unroll
        for (int ct = 0; ct < 4; ++ct)
            acc[m][ct] = (f32x4){0.f, 0.f, 0.f, 0.f};

    int colin = lane & 15;
    #pragma unroll
    for (int m = 0; m < 3; ++m) {
        const ushort_t* Wm = Wt + m * 4096;
        #pragma unroll
        for (int ct = 0; ct < 4; ++ct) {
            const ushort_t* wb = &Wm[(ct * 16 + colin) * 64 + koff];
            #pragma unroll
            for (int kh = 0; kh < 2; ++kh) {
                U8 wf;
                wf.u = *(const uint4*)(wb + kh * 32);
                acc[m][ct] = __builtin_amdgcn_mfma_f32_16x16x32_bf16(
                    wf.b, xf[kh].b, acc[m][ct], 0, 0, 0);
            }
        }
    }

    if (node < N_NODES) {
        int wc4 = (lane >> 4) * 4;
        #pragma unroll
        for (int ct = 0; ct < 4; ++ct) {
            int wc = ct * 16 + wc4;        // output col: head = wc>>3, dim = wc&7
            float4 qb = *(const float4*)&bq[wc];
            f32x4 a = acc[0][ct];
            *(uint2*)&Qb[(size_t)node * 64 + wc] =
                make_uint2(pkbf16(a[0] + qb.x, a[1] + qb.y),
                           pkbf16(a[2] + qb.z, a[3] + qb.w));
            int hh = wc >> 3;
            ushort_t* kvdst = (hh < 4 ? KVlo : KVhi)
                            + (size_t)node * 64 + (hh & 3) * 8 + (wc & 7);
            float4 kb = *(const float4*)&bk[wc];
            f32x4 k = acc[1][ct];
            *(uint2*)kvdst =
                make_uint2(pkbf16(k[0] + kb.x, k[1] + kb.y),
                           pkbf16(k[2] + kb.z, k[3] + kb.w));
            float4 vb = *(const float4*)&bv[wc];
            f32x4 v = acc[2][ct];
            *(uint2*)(kvdst + 32) =
                make_uint2(pkbf16(v[0] + vb.x, v[1] + vb.y),
                           pkbf16(v[2] + vb.z, v[3] + vb.w));
        }
    }
}

// ---------------------------------------------------------------------------
// Pass 1: bucket scatter, 1024 threads x 8192 edges per block (196 blocks).
// ---------------------------------------------------------------------------
__global__ __launch_bounds__(1024) void scatter_kernel(
    const int* __restrict__ ei, int* __restrict__ cursor,
    unsigned int* __restrict__ pairs)
{
    __shared__ int hist[NBUCKETS];
    __shared__ int bbs[NBUCKETS];
    int t = threadIdx.x;
    for (int i = t; i < NBUCKETS; i += 1024) hist[i] = 0;
    __syncthreads();

    const int4* r4 = (const int4*)ei;
    const int4* c4 = (const int4*)(ei + N_EDGES);
    int ia = blockIdx.x * 2048 + t;
    int ib = ia + 1024;
    bool va = (ia < N_EDGES / 4), vb = (ib < N_EDGES / 4);
    int4 rva = va ? r4[ia] : make_int4(0, 0, 0, 0);
    int4 cva = va ? c4[ia] : make_int4(0, 0, 0, 0);
    int4 rvb = vb ? r4[ib] : make_int4(0, 0, 0, 0);
    int4 cvb = vb ? c4[ib] : make_int4(0, 0, 0, 0);

    int rr[8], cc[8];
    rr[0] = rva.x; rr[1] = rva.y; rr[2] = rva.z; rr[3] = rva.w;
    rr[4] = rvb.x; rr[5] = rvb.y; rr[6] = rvb.z; rr[7] = rvb.w;
    cc[0] = cva.x; cc[1] = cva.y; cc[2] = cva.z; cc[3] = cva.w;
    cc[4] = cvb.x; cc[5] = cvb.y; cc[6] = cvb.z; cc[7] = cvb.w;

    int bkt[8], rnk[8];
    unsigned pk[8];
    #pragma unroll
    for (int j = 0; j < 8; ++j) {
        bool v = (j < 4) ? va : vb;
        int b = rr[j] >> BUCKET_SHIFT;
        bkt[j] = b;
        rnk[j] = v ? atomicAdd(&hist[b], 1) : 0;
        pk[j] = ((unsigned)(rr[j] & 255) << 17) | (unsigned)cc[j];
    }
    __syncthreads();
    for (int i = t; i < NBUCKETS; i += 1024) {
        int h = hist[i];
        if (h) bbs[i] = i * BCAP + atomicAdd(&cursor[i], h);
    }
    __syncthreads();
    #pragma unroll
    for (int j = 0; j < 8; ++j) {
        bool v = (j < 4) ? va : vb;
        if (v) pairs[bbs[bkt[j]] + rnk[j]] = pk[j];
    }
}

// ---------------------------------------------------------------------------
// Pass 2: one block per bucket, 512 threads. Stage pairs in LDS; 4096-bin
// histogram keyed (node_local<<4 | col/6250) -> each node's edge list is
// ordered by 16 col-chunks of 0.8 MB/half (L2 cache blocking for agg).
// Scan over first 256 threads. Writes ordered col ids back IN PLACE.
// ---------------------------------------------------------------------------
__global__ __launch_bounds__(512) void csr_build_kernel(
    unsigned int* __restrict__ pairs, const int* __restrict__ cursor,
    int* __restrict__ deg, int* __restrict__ start)
{
    __shared__ unsigned int lp[BCAP];        // 24 KB
    __shared__ int hist[4096];               // 16 KB
    __shared__ int wsum[4];
    int b = blockIdx.x, t = threadIdx.x;
    int cnt = cursor[b];
    unsigned int* bp = pairs + (size_t)b * BCAP;

    for (int i = t; i < cnt; i += 512) lp[i] = bp[i];
    for (int i = t; i < 4096; i += 512) hist[i] = 0;
    __syncthreads();
    for (int i = t; i < cnt; i += 512) {
        unsigned p = lp[i];
        unsigned col = p & 0x1FFFFu;
        int key = (int)((p >> 17) << 4) | (int)(col / CCHUNK);
        atomicAdd(&hist[key], 1);
    }
    __syncthreads();

    // threads 0..255: thread t owns node-bin t (16 chunk bins)
    if (t < 256) {
        int hv[16];
        int local = 0;
        #pragma unroll
        for (int c = 0; c < 16; ++c) { hv[c] = hist[16 * t + c]; local += hv[c]; }
        int lane = t & 63, w = t >> 6;
        int inc = local;
        #pragma unroll
        for (int off = 1; off < 64; off <<= 1) {
            int u = __shfl_up(inc, off);
            if (lane >= off) inc += u;
        }
        if (lane == 63) wsum[w] = inc;
        __syncthreads();
        int woff = 0;
        for (int i = 0; i < w; ++i) woff += wsum[i];
        int excl = woff + inc - local;
        int node = (b << BUCKET_SHIFT) + t;
        if (node < N_NODES) { deg[node] = local; start[node] = b * BCAP + excl; }
        int run = excl;
        #pragma unroll
        for (int c = 0; c < 16; ++c) { hist[16 * t + c] = run; run += hv[c]; }
    } else {
        __syncthreads();                     // match barrier in the t<256 path
    }
    __syncthreads();
    for (int i = t; i < cnt; i += 512) {
        unsigned p = lp[i];
        unsigned col = p & 0x1FFFFu;
        int key = (int)((p >> 17) << 4) | (int)(col / CCHUNK);
        int pos = atomicAdd(&hist[key], 1);
        bp[pos] = col;
    }
}

// ---------------------------------------------------------------------------
// K6 (R19 optimum, reverted from R20): per-node softmax aggregation over
// HALF-HEAD tables. Lane = (node-slot = lane>>2, h2 = lane&3), 16 nodes x
// 4 heads per wave, ILP-2. 12504 waves (1.5 occupancy rounds) measured
// FASTER than the 6256-wave all-resident variant (R20: -35% MLP, +15%
// FETCH from 32-node tail divergence). Edge lists col-chunk-ordered ->
// gather stream L2-blocked. s/acc lane-local, zero cross-lane ops.
// ---------------------------------------------------------------------------
#define DOT8H(KW) (blo(KW.x) * q0 + bhi(KW.x) * q1                            \
                 + blo(KW.y) * q2 + bhi(KW.y) * q3                            \
                 + blo(KW.z) * q4 + bhi(KW.z) * q5                            \
                 + blo(KW.w) * q6 + bhi(KW.w) * q7)

#define ACC8H(P, VW)                                                          \
    acc[0] = fmaf(P, blo(VW.x), acc[0]);                                      \
    acc[1] = fmaf(P, bhi(VW.x), acc[1]);                                      \
    acc[2] = fmaf(P, blo(VW.y), acc[2]);                                      \
    acc[3] = fmaf(P, bhi(VW.y), acc[3]);                                      \
    acc[4] = fmaf(P, blo(VW.z), acc[4]);                                      \
    acc[5] = fmaf(P, bhi(VW.z), acc[5]);                                      \
    acc[6] = fmaf(P, blo(VW.w), acc[6]);                                      \
    acc[7] = fmaf(P, bhi(VW.w), acc[7]);

__global__ __launch_bounds__(256) void agg_kernel(
    const ushort_t* __restrict__ Qb, const ushort_t* __restrict__ KVlo,
    const ushort_t* __restrict__ KVhi,
    const int* __restrict__ start, const int* __restrict__ deg,
    const int* __restrict__ elist, ushort_t* __restrict__ aggb)
{
    int bid = blockIdx.x;
    int grp = bid & 7;
    int half = grp >> 2;                     // XCDs 0-3 -> lo, 4-7 -> hi
    int k = (bid >> 3) * 4 + (grp & 3);      // 64-node chunk id
    if (k >= NCHUNKS) return;

    int tid = threadIdx.x;
    int lane = tid & 63;
    int ns = lane >> 2;                      // node slot 0..15
    int h2 = lane & 3;                       // head within half
    int n = k * 64 + (tid >> 6) * 16 + ns;
    bool valid = n < N_NODES;
    int nc = valid ? n : N_NODES - 1;

    int d = deg[nc];
    int st = start[nc];
    const ushort_t* KV = half ? KVhi : KVlo;

    uint4 qw = *(const uint4*)&Qb[(size_t)nc * 64 + (half * 4 + h2) * 8];
    float q0 = blo(qw.x), q1 = bhi(qw.x), q2 = blo(qw.y), q3 = bhi(qw.y);
    float q4 = blo(qw.z), q5 = bhi(qw.z), q6 = blo(qw.w), q7 = bhi(qw.w);

    const float inv_scale = 0.35355339059327373f;  // 1/sqrt(8)
    float s = 0.f;
    float acc[8] = {0.f, 0.f, 0.f, 0.f, 0.f, 0.f, 0.f, 0.f};

    int j = 0;
    for (; j + 2 <= d; j += 2) {
        int c0 = elist[st + j];
        int c1 = elist[st + j + 1];
        const ushort_t* r0 = KV + (size_t)c0 * 64 + h2 * 8;
        const ushort_t* r1 = KV + (size_t)c1 * 64 + h2 * 8;
        uint4 kw0 = *(const uint4*)r0;
        uint4 kw1 = *(const uint4*)r1;
        uint4 vw0 = *(const uint4*)(r0 + 32);
        uint4 vw1 = *(const uint4*)(r1 + 32);
        float p0 = __expf(DOT8H(kw0) * inv_scale);
        float p1 = __expf(DOT8H(kw1) * inv_scale);
        s += p0 + p1;
        ACC8H(p0, vw0)
        ACC8H(p1, vw1)
    }
    if (j < d) {
        int c0 = elist[st + j];
        const ushort_t* r0 = KV + (size_t)c0 * 64 + h2 * 8;
        uint4 kw0 = *(const uint4*)r0;
        uint4 vw0 = *(const uint4*)(r0 + 32);
        float p0 = __expf(DOT8H(kw0) * inv_scale);
        s += p0;
        ACC8H(p0, vw0)
    }

    if (valid) {
        float inv = 1.f / (s + 1e-8f);
        *(uint4*)&aggb[(size_t)n * 64 + (half * 4 + h2) * 8] = make_uint4(
            pkbf16(acc[0] * inv, acc[1] * inv), pkbf16(acc[2] * inv, acc[3] * inv),
            pkbf16(acc[4] * inv, acc[5] * inv), pkbf16(acc[6] * inv, acc[7] * inv));
    }
}

// ---------------------------------------------------------------------------
// K7: output projection via MFMA. B-fragments load DIRECTLY from bf16 aggb.
// ---------------------------------------------------------------------------
__global__ __launch_bounds__(256) void out_kernel(
    const ushort_t* __restrict__ aggb, const ushort_t* __restrict__ Wto,
    const float* __restrict__ bo, float* __restrict__ out)
{
    int tid = threadIdx.x;
    int lane = tid & 63;
    int w = tid >> 6;
    int node = blockIdx.x * 64 + w * 16 + (lane & 15);
    int nclamp = node < N_NODES ? node : N_NODES - 1;
    int koff = (lane >> 4) * 8;

    U8 af[2];
    #pragma unroll
    for (int kh = 0; kh < 2; ++kh)
        af[kh].u = *(const uint4*)&aggb[(size_t)nclamp * 64 + kh * 32 + koff];

    f32x4 acc[4];
    #pragma unroll
    for (int ct = 0; ct < 4; ++ct) acc[ct] = (f32x4){0.f, 0.f, 0.f, 0.f};

    int colin = lane & 15;
    #pragma unroll
    for (int ct = 0; ct < 4; ++ct) {
        const ushort_t* wb = &Wto[(ct * 16 + colin) * 64 + koff];
        #pragma unroll
        for (int kh = 0; kh < 2; ++kh) {
            U8 wf;
            wf.u = *(const uint4*)(wb + kh * 32);
            acc[ct] = __builtin_amdgcn_mfma_f32_16x16x32_bf16(
                wf.b, af[kh].b, acc[ct], 0, 0, 0);
        }
    }

    if (node < N_NODES) {
        int wc4 = (lane >> 4) * 4;
        #pragma unroll
        for (int ct = 0; ct < 4; ++ct) {
            int wc = ct * 16 + wc4;
            float4 ob = *(const float4*)&bo[wc];
            f32x4 a = acc[ct];
            *(float4*)&out[(size_t)node * 64 + wc] =
                make_float4(a[0] + ob.x, a[1] + ob.y, a[2] + ob.z, a[3] + ob.w);
        }
    }
}

extern "C" void kernel_launch(void* const* d_in, const int* in_sizes, int n_in,
                              void* d_out, int out_size, void* d_ws, size_t ws_size,
                              hipStream_t stream)
{
    const float* x  = (const float*)d_in[0];
    const int*   ei = (const int*)  d_in[1];   // [2*E] flattened: row then col
    const float* Wq = (const float*)d_in[2];
    const float* bq = (const float*)d_in[3];
    const float* Wk = (const float*)d_in[4];
    const float* bk = (const float*)d_in[5];
    const float* Wv = (const float*)d_in[6];
    const float* bv = (const float*)d_in[7];
    const float* Wo = (const float*)d_in[8];
    const float* bo = (const float*)d_in[9];
    float* out = (float*)d_out;

    ushort_t* Qb   = (ushort_t*)d_ws;                      // N*64 bf16   12.8 MB
    ushort_t* KVlo = Qb + (size_t)N_NODES * 64;            // N*64 bf16   12.8 MB
    ushort_t* KVhi = KVlo + (size_t)N_NODES * 64;          // N*64 bf16   12.8 MB
    ushort_t* aggb = KVhi + (size_t)N_NODES * 64;          // N*64 bf16   12.8 MB
    int* deg    = (int*)(aggb + (size_t)N_NODES * 64);
    int* start  = deg + N_NODES;
    int* cursor = start + N_NODES;                         // 512 ints
    unsigned int* pairs = (unsigned int*)(cursor + 512);   // NBUCKETS*BCAP (elist aliases)
    ushort_t* Wt = (ushort_t*)(pairs + (size_t)NBUCKETS * BCAP);  // 4*64*64 bf16

    wtrans_kernel<<<1, 256, 0, stream>>>(Wq, Wk, Wv, Wo, Wt, cursor);
    qkv_kernel<<<NPROJ_BLOCKS, 256, 0, stream>>>(x, Wt, bq, bk, bv, Qb, KVlo, KVhi);
    scatter_kernel<<<SCAT_BLOCKS, 1024, 0, stream>>>(ei, cursor, pairs);
    csr_build_kernel<<<NBUCKETS, 512, 0, stream>>>(pairs, cursor, deg, start);
    agg_kernel<<<((NCHUNKS + 3) / 4) * 8, 256, 0, stream>>>(
        Qb, KVlo, KVhi, start, deg, (const int*)pairs, aggb);
    out_kernel<<<NPROJ_BLOCKS, 256, 0, stream>>>(aggb, Wt + 3 * 4096, bo, out);
}